// Round 4
// baseline (114.531 us; speedup 1.0000x reference)
//
#include <hip/hip_runtime.h>

// Problem constants
#define NDIM 471
#define MD   128
#define TD   16384
#define KSEL 50
#define CGIT 24
#define WN   472            // W column count: 471 qt columns + 1 extra RHS (t1 = Q w)

// ws float-offset layout
#define WS_PART   0                 // [256][471] column-sum partials
#define WS_G      120832            // [128][128] Gram
#define WS_T1     137216            // [128]  t1 = Q w
#define WS_W      137472            // [128][472] W = Ginv @ [Q | t1] (via CG)
#define WS_XBAR   197888            // [471]
#define WS_W2     198400            // [471]
#define WS_R      198912            // [471][471] R = (alpha/N) Q^T Ginv Q

// SGPR broadcast: readlane with compile-time lane index -> v_readlane_b32 s,v,imm
static __device__ __forceinline__ float rdl(float v, int lane){
    return __int_as_float(__builtin_amdgcn_readlane(__float_as_int(v), lane));
}

// ---- Kernel 1: blocks 0..255 Gram; 256..511 colsum partials; 512 t1 = Q w ----
__global__ __launch_bounds__(512) void k_gram_colsum(const float* __restrict__ qt,
                                                     const float* __restrict__ x,
                                                     const float* __restrict__ wv,
                                                     float* __restrict__ ws){
    int lane = threadIdx.x & 63, wid = threadIdx.x >> 6;
    if (blockIdx.x < 256){
        float* G = ws + WS_G;
        int gw = blockIdx.x * 8 + wid;          // 0..2047 waves
        int i = gw >> 4, jb = gw & 15;
        float qi[8];
#pragma unroll
        for (int s = 0; s < 8; ++s){ int idx = lane + 64*s; qi[s] = (idx < NDIM) ? qt[i*NDIM + idx] : 0.f; }
#pragma unroll
        for (int t = 0; t < 8; ++t){
            int j = jb + 16*t;
            float acc = 0.f;
#pragma unroll
            for (int s = 0; s < 8; ++s){
                int idx = lane + 64*s;
                float qj = (idx < NDIM) ? qt[j*NDIM + idx] : 0.f;
                acc = fmaf(qi[s], qj, acc);
            }
#pragma unroll
            for (int d = 1; d < 64; d <<= 1) acc += __shfl_xor(acc, d);
            if (lane == 0) G[i*MD + j] = acc;
        }
    } else if (blockIdx.x < 512){
        int cb = blockIdx.x - 256;              // 0..255, rows cb*64..+64
        int col = threadIdx.x;
        if (col < NDIM){
            const float* xp = x + (size_t)cb*64*NDIM + col;
            float acc = 0.f;
#pragma unroll 4
            for (int r = 0; r < 64; ++r) acc += xp[(size_t)r*NDIM];
            ws[WS_PART + cb*NDIM + col] = acc;
        }
    } else {
        // t1[m] = sum_idx qt[m][idx] * w[idx]
        for (int m = wid; m < MD; m += 8){
            float acc = 0.f;
#pragma unroll
            for (int s = 0; s < 8; ++s){
                int idx = lane + 64*s;
                if (idx < NDIM) acc = fmaf(qt[m*NDIM + idx], wv[idx], acc);
            }
#pragma unroll
            for (int d = 1; d < 64; d <<= 1) acc += __shfl_xor(acc, d);
            if (lane == 0) ws[WS_T1 + m] = acc;
        }
    }
}

// ---- Kernel 2: blocks 0..117 CG (4 cols/block, SGPR-broadcast matvec); 118..176 xbar ----
__global__ __launch_bounds__(512, 2) void k_cg_xbar(const float* __restrict__ qt, float* __restrict__ ws){
    int tid = threadIdx.x, lane = tid & 63, wid = tid >> 6;
    if (blockIdx.x < 118){
        __shared__ __align__(16) float rl[4][128];
        __shared__ float red2[8][2];
        int g = tid >> 7, r = tid & 127;
        int col = blockIdx.x*4 + g;             // 0..471 (472 = 118*4; col 471 = t1 RHS)
        float Grow[128];
        const float* Gp = ws + WS_G + r*MD;
#pragma unroll
        for (int k4 = 0; k4 < 32; ++k4){
            float4 gv = *(const float4*)(Gp + 4*k4);
            Grow[4*k4+0]=gv.x; Grow[4*k4+1]=gv.y; Grow[4*k4+2]=gv.z; Grow[4*k4+3]=gv.w;
        }
        float bvv = (col < NDIM) ? qt[r*NDIM + col] : ws[WS_T1 + r];
        float xv = 0.f, rv = bvv, pv = 0.f, sv = 0.f, gam = 1.f, alf = 1.f;
        for (int it = 0; it < CGIT; ++it){
            rl[g][r] = rv;
            __syncthreads();
            // whole r-vector into 4 VGPRs/lane: lane c holds chunk c = r[4c..4c+3]
            float4 pch = ((const float4*)rl[g])[lane & 31];
            // w = G r via SGPR broadcast (readlane imm) + 4 split FMA chains
            float y0=0.f, y1=0.f, y2=0.f, y3=0.f;
#pragma unroll
            for (int c = 0; c < 32; ++c){
                float p0 = rdl(pch.x, c), p1 = rdl(pch.y, c), p2 = rdl(pch.z, c), p3 = rdl(pch.w, c);
                y0 = fmaf(Grow[4*c+0], p0, y0);
                y1 = fmaf(Grow[4*c+1], p1, y1);
                y2 = fmaf(Grow[4*c+2], p2, y2);
                y3 = fmaf(Grow[4*c+3], p3, y3);
            }
            float w = (y0+y1) + (y2+y3);
            // fused dots: gamma' = (r,r), delta = (w,r)
            float t0 = rv*rv, t1 = w*rv;
#pragma unroll
            for (int d = 1; d < 64; d <<= 1){ t0 += __shfl_xor(t0, d); t1 += __shfl_xor(t1, d); }
            if (lane == 0){ red2[wid][0] = t0; red2[wid][1] = t1; }
            __syncthreads();
            float gp = red2[2*g][0] + red2[2*g+1][0];
            float dl = red2[2*g][1] + red2[2*g+1][1];
            float bet, anew;
            if (it == 0){ bet = 0.f; anew = gp / fmaxf(dl, 1e-30f); }
            else { bet = gp / fmaxf(gam, 1e-30f); anew = gp / fmaxf(dl - bet*gp/alf, 1e-30f); }
            pv = fmaf(bet, pv, rv);
            sv = fmaf(bet, sv, w);
            xv = fmaf(anew, pv, xv);
            rv = fmaf(-anew, sv, rv);
            gam = gp; alf = anew;
        }
        ws[WS_W + r*WN + col] = xv;
    } else {
        // xbar finalize: 8 columns per block, 256 partial rows
        __shared__ float part[8][8];
        int b2 = blockIdx.x - 118;              // 0..58
        int cl = tid & 7, seg = tid >> 3;       // seg 0..63
        int col = b2*8 + cl;
        float acc = 0.f;
        if (col < NDIM){
#pragma unroll
            for (int q = 0; q < 4; ++q) acc += ws[WS_PART + (seg*4 + q)*NDIM + col];
        }
        acc += __shfl_xor(acc, 8);
        acc += __shfl_xor(acc, 16);
        acc += __shfl_xor(acc, 32);
        if (lane < 8) part[wid][lane] = acc;    // lane<8 => cl==lane
        __syncthreads();
        if (tid < 8){
            float t = 0.f;
#pragma unroll
            for (int w2 = 0; w2 < 8; ++w2) t += part[w2][tid];
            int c2 = b2*8 + tid;
            if (c2 < NDIM) ws[WS_XBAR + c2] = t * (1.0f / TD);
        }
    }
}

// ---- Kernel 3: blocks 0..117 = W2 = lw@xbar + lb; blocks 118..588 = R rows ----
__global__ __launch_bounds__(256) void k_w2_r(const float* __restrict__ qt, const float* __restrict__ lw,
                                              const float* __restrict__ lb, const float* __restrict__ alpha,
                                              float* __restrict__ ws){
    if (blockIdx.x < 118){
        int lane = threadIdx.x & 63, wid = threadIdx.x >> 6;
        int i = blockIdx.x*4 + wid;
        if (i < NDIM){
            float acc = 0.f;
#pragma unroll
            for (int s = 0; s < 8; ++s){
                int idx = lane + 64*s;
                if (idx < NDIM) acc = fmaf(lw[(size_t)i*NDIM + idx], ws[WS_XBAR + idx], acc);
            }
#pragma unroll
            for (int d = 1; d < 64; d <<= 1) acc += __shfl_xor(acc, d);
            if (lane == 0) ws[WS_W2 + i] = acc + lb[i];
        }
    } else {
        int i = blockIdx.x - 118;           // 0..470 : row i of R
        __shared__ __align__(16) float qc[MD];
        int tid = threadIdx.x, lane = tid & 63;
        if (tid < MD) qc[tid] = qt[tid*NDIM + i];
        __syncthreads();
        float4 qv = ((const float4*)qc)[lane & 31];
        float sc = alpha[0] / (float)NDIM;
        const float* Wp = ws + WS_W;
        int j0 = tid;
        int j1 = (tid + 256 < NDIM) ? tid + 256 : (NDIM - 1);   // clamp (guarded store)
        float a0=0.f, a1=0.f, a2=0.f, a3=0.f;
        float b0=0.f, b1=0.f, b2=0.f, b3=0.f;
#pragma unroll 8
        for (int c = 0; c < 32; ++c){
            float p0 = rdl(qv.x, c), p1 = rdl(qv.y, c), p2 = rdl(qv.z, c), p3 = rdl(qv.w, c);
            const float* W0 = Wp + (4*c+0)*WN;
            const float* W1 = Wp + (4*c+1)*WN;
            const float* W2 = Wp + (4*c+2)*WN;
            const float* W3 = Wp + (4*c+3)*WN;
            a0 = fmaf(p0, W0[j0], a0); b0 = fmaf(p0, W0[j1], b0);
            a1 = fmaf(p1, W1[j0], a1); b1 = fmaf(p1, W1[j1], b1);
            a2 = fmaf(p2, W2[j0], a2); b2 = fmaf(p2, W2[j1], b2);
            a3 = fmaf(p3, W3[j0], a3); b3 = fmaf(p3, W3[j1], b3);
        }
        if (j0 < NDIM) ws[WS_R + (size_t)i*NDIM + j0] = sc * ((a0+a1) + (a2+a3));
        if (tid + 256 < NDIM) ws[WS_R + (size_t)i*NDIM + tid + 256] = sc * ((b0+b1) + (b2+b3));
    }
}

// ---- Kernel 4: the 10-iteration solver (single block; 6 barriers/iter) ----
__global__ __launch_bounds__(512) void k_iter(const float* __restrict__ qt, const float* __restrict__ wv,
                                              const float* __restrict__ alpha, const float* __restrict__ lamda,
                                              const float* __restrict__ rho_p, const float* __restrict__ mu_p,
                                              const float* __restrict__ ws, float* __restrict__ out){
    int tid = threadIdx.x, lane = tid & 63, wid = tid >> 6;
    bool act = tid < NDIM;
    float rho = rho_p[0], mu = mu_p[0], lam = lamda[0];
    float sc  = alpha[0] / (float)NDIM;
    float wi  = act ? wv[tid]         : 0.f;
    float W2i = act ? ws[WS_W2 + tid] : 0.f;

    __shared__ __align__(16) unsigned bins[1024];   // 4 buffers x 256 bins
    __shared__ float t2l[128];
    __shared__ int   slist[64];
    __shared__ float swl[64];
    __shared__ float warr[8];
    __shared__ unsigned wcnt[8];

    bins[tid] = 0u; bins[tid + 512] = 0u;
    if (tid < MD) t2l[tid] = ws[WS_W + tid*WN + 471];   // t2 = Ginv (Q w)
    __syncthreads();

    // Rw_i = sc * sum_k qt[k][i] * t2[k]   (coalesced qt column reads, L2-hot)
    float Rwi = 0.f;
    if (act){
        float a0=0.f, a1=0.f, a2=0.f, a3=0.f;
#pragma unroll
        for (int k = 0; k < MD; k += 4){
            a0 = fmaf(qt[(k+0)*NDIM + tid], t2l[k+0], a0);
            a1 = fmaf(qt[(k+1)*NDIM + tid], t2l[k+1], a1);
            a2 = fmaf(qt[(k+2)*NDIM + tid], t2l[k+2], a2);
            a3 = fmaf(qt[(k+3)*NDIM + tid], t2l[k+3], a3);
        }
        Rwi = sc * ((a0+a1) + (a2+a3));
    }

    float z = 0.f, u = 0.f, Ruv = 0.f, Rzv = 0.f, Sz = 0.f;
    for (int it = 0; it < 10; ++it){
        float Rv = Ruv - rho*(Rzv - Rwi);
        float b  = wi + Rv;
        float grad = W2i + rho*(z - b) + u + 2.f*lam*(Sz - 1.f);
        float zn = z - mu*grad;
        zn = (act && zn > 0.f) ? zn : 0.f;
        unsigned bits = __float_as_uint(zn);

        // radix select: 1 barrier/pass; per-pass private bin buffer; redundant per-wave scan
        unsigned prefix = 0, need = KSEL;
#pragma unroll
        for (int pass = 3; pass >= 0; --pass){
            int sh = pass*8;
            unsigned* bp = bins + ((3 - pass) << 8);
            bool av = (pass == 3) || ((bits >> (sh + 8)) == (prefix >> (sh + 8)));
            if (av) atomicAdd(&bp[(bits >> sh) & 255u], 1u);
            __syncthreads();
            int base = 255 - 4*lane;
            uint4 bq = *(const uint4*)&bp[base - 3];
            unsigned b3 = bq.x, b2 = bq.y, b1 = bq.z, b0 = bq.w;   // b0 = bp[base] (highest)
            unsigned csum = b0 + b1 + b2 + b3;
            unsigned incl = csum;
#pragma unroll
            for (int d = 1; d < 64; d <<= 1){ unsigned t = __shfl_up(incl, d); if (lane >= d) incl += t; }
            unsigned excl = incl - csum;
            bool hit = (excl < need) && (need <= incl);
            unsigned long long hm = __ballot(hit);
            int hl = __ffsll((long long)hm) - 1;
            unsigned c0 = excl + b0, c1 = c0 + b1, c2 = c1 + b2;
            int byte; unsigned above;
            if      (need <= c0){ byte = base;   above = excl; }
            else if (need <= c1){ byte = base-1; above = c0; }
            else if (need <= c2){ byte = base-2; above = c1; }
            else                { byte = base-3; above = c2; }
            byte  = __shfl(byte, hl);
            above = (unsigned)__shfl((int)above, hl);
            prefix |= ((unsigned)byte) << sh;
            need -= above;
        }
        z = (act && bits >= prefix) ? zn : 0.f;

        // Sz + support list
        bool flag = z > 0.f;
        unsigned long long mb = __ballot(flag);
        float v = z;
#pragma unroll
        for (int d = 1; d < 64; d <<= 1) v += __shfl_xor(v, d);
        if (lane == 0){ warr[wid] = v; wcnt[wid] = (unsigned)__popcll(mb); }
        __syncthreads();
        Sz = ((warr[0]+warr[1])+(warr[2]+warr[3])) + ((warr[4]+warr[5])+(warr[6]+warr[7]));

        if (it < 9){
            unsigned off = 0;
#pragma unroll
            for (int w2 = 0; w2 < 8; ++w2) if (w2 < wid) off += wcnt[w2];
            off += (unsigned)__popcll(mb & ((1ull << lane) - 1ull));
            int cnt = 0;
#pragma unroll
            for (int w2 = 0; w2 < 8; ++w2) cnt += (int)wcnt[w2];
            if (flag){ slist[off] = tid; swl[off] = z; }
            if (tid >= cnt && tid < 56){ slist[tid] = 0; swl[tid] = 0.f; }   // exact pad (w=0)
            bins[tid] = 0u; bins[tid + 512] = 0u;   // re-zero for next iteration
            __syncthreads();

            // Rz_new over fixed 56-trip fully-unrolled pipeline (4 acc chains)
            float acc = 0.f;
            if (act){
                const float* Rb = ws + WS_R;
                float a0=0.f, a1=0.f, a2=0.f, a3=0.f;
#pragma unroll
                for (int s = 0; s < 56; s += 4){
                    int j0 = slist[s], j1 = slist[s+1], j2 = slist[s+2], j3 = slist[s+3];
                    a0 = fmaf(Rb[(size_t)j0*NDIM + tid], swl[s+0], a0);
                    a1 = fmaf(Rb[(size_t)j1*NDIM + tid], swl[s+1], a1);
                    a2 = fmaf(Rb[(size_t)j2*NDIM + tid], swl[s+2], a2);
                    a3 = fmaf(Rb[(size_t)j3*NDIM + tid], swl[s+3], a3);
                }
                acc = (a0+a1) + (a2+a3);
            }
            float Rbv = Rwi + sc*Rv;                // R@b = Rw + (alpha/N)*Rv   (P^2 = P)
            u   += rho*(z - b);
            Ruv += rho*(acc - Rbv);
            Rzv  = acc;
        }
    }
    if (act) out[tid] = z / (Sz + 1e-8f);
}

extern "C" void kernel_launch(void* const* d_in, const int* in_sizes, int n_in,
                              void* d_out, int out_size, void* d_ws, size_t ws_size,
                              hipStream_t stream) {
    const float* x     = (const float*)d_in[0];
    const float* qt    = (const float*)d_in[1];
    const float* wv    = (const float*)d_in[2];
    // d_in[3] = b1 (unused by forward math)
    const float* alpha = (const float*)d_in[4];
    const float* lamda = (const float*)d_in[5];
    const float* rho   = (const float*)d_in[6];
    const float* mu    = (const float*)d_in[7];
    const float* lw    = (const float*)d_in[8];
    const float* lb    = (const float*)d_in[9];
    float* out = (float*)d_out;
    float* ws  = (float*)d_ws;

    k_gram_colsum<<<513, 512, 0, stream>>>(qt, x, wv, ws);
    k_cg_xbar    <<<177, 512, 0, stream>>>(qt, ws);
    k_w2_r       <<<589, 256, 0, stream>>>(qt, lw, lb, alpha, ws);
    k_iter       <<<1,   512, 0, stream>>>(qt, wv, alpha, lamda, rho, mu, ws, out);
}

// Round 5
// 101.776 us; speedup vs baseline: 1.1253x; 1.1253x over previous
//
#include <hip/hip_runtime.h>

// Problem constants
#define NDIM 471
#define MD   128
#define TD   16384
#define KSEL 50
#define CGIT 24
#define WN   472            // W column count: 471 qt columns + 1 extra RHS (t1 = Q w)

// ws float-offset layout (ends 421265 floats = 1.69 MB; R1 used 1.75 MB OK)
#define WS_PART   0                 // [256][471] column-sum partials
#define WS_G      120832            // [128][128] Gram
#define WS_T1     137216            // [128]  t1 = Q w
#define WS_W      137472            // [128][472] W = Ginv @ [Q | t1] (via CG)
#define WS_XBAR   197888            // [471]
#define WS_W2     198400            // [471]
#define WS_RW     198912            // [471]  Rw = R @ w
#define WS_R      199424            // [471][471] R = (alpha/N) Q^T Ginv Q

// SGPR broadcast: readlane with compile-time lane index -> v_readlane_b32 s,v,imm
static __device__ __forceinline__ float rdl(float v, int lane){
    return __int_as_float(__builtin_amdgcn_readlane(__float_as_int(v), lane));
}

// ---- Kernel 1: blocks 0..255 Gram; 256..511 colsum partials; 512 t1 = Q w ----
__global__ __launch_bounds__(512) void k_gram_colsum(const float* __restrict__ qt,
                                                     const float* __restrict__ x,
                                                     const float* __restrict__ wv,
                                                     float* __restrict__ ws){
    int lane = threadIdx.x & 63, wid = threadIdx.x >> 6;
    if (blockIdx.x < 256){
        float* G = ws + WS_G;
        int gw = blockIdx.x * 8 + wid;          // 0..2047 waves
        int i = gw >> 4, jb = gw & 15;
        float qi[8];
#pragma unroll
        for (int s = 0; s < 8; ++s){ int idx = lane + 64*s; qi[s] = (idx < NDIM) ? qt[i*NDIM + idx] : 0.f; }
#pragma unroll
        for (int t = 0; t < 8; ++t){
            int j = jb + 16*t;
            float acc = 0.f;
#pragma unroll
            for (int s = 0; s < 8; ++s){
                int idx = lane + 64*s;
                float qj = (idx < NDIM) ? qt[j*NDIM + idx] : 0.f;
                acc = fmaf(qi[s], qj, acc);
            }
#pragma unroll
            for (int d = 1; d < 64; d <<= 1) acc += __shfl_xor(acc, d);
            if (lane == 0) G[i*MD + j] = acc;
        }
    } else if (blockIdx.x < 512){
        int cb = blockIdx.x - 256;              // 0..255, rows cb*64..+64
        int col = threadIdx.x;
        if (col < NDIM){
            const float* xp = x + (size_t)cb*64*NDIM + col;
            float acc = 0.f;
#pragma unroll 4
            for (int r = 0; r < 64; ++r) acc += xp[(size_t)r*NDIM];
            ws[WS_PART + cb*NDIM + col] = acc;
        }
    } else {
        // t1[m] = sum_idx qt[m][idx] * w[idx]
        for (int m = wid; m < MD; m += 8){
            float acc = 0.f;
#pragma unroll
            for (int s = 0; s < 8; ++s){
                int idx = lane + 64*s;
                if (idx < NDIM) acc = fmaf(qt[m*NDIM + idx], wv[idx], acc);
            }
#pragma unroll
            for (int d = 1; d < 64; d <<= 1) acc += __shfl_xor(acc, d);
            if (lane == 0) ws[WS_T1 + m] = acc;
        }
    }
}

// ---- Kernel 2: blocks 0..117 CG (4 cols/block, SGPR-broadcast matvec); 118..176 xbar ----
__global__ __launch_bounds__(512, 2) void k_cg_xbar(const float* __restrict__ qt, float* __restrict__ ws){
    int tid = threadIdx.x, lane = tid & 63, wid = tid >> 6;
    if (blockIdx.x < 118){
        __shared__ __align__(16) float rl[4][128];
        __shared__ float red2[8][2];
        int g = tid >> 7, r = tid & 127;
        int col = blockIdx.x*4 + g;             // 0..471 (472 = 118*4; col 471 = t1 RHS)
        float Grow[128];
        const float* Gp = ws + WS_G + r*MD;
#pragma unroll
        for (int k4 = 0; k4 < 32; ++k4){
            float4 gv = *(const float4*)(Gp + 4*k4);
            Grow[4*k4+0]=gv.x; Grow[4*k4+1]=gv.y; Grow[4*k4+2]=gv.z; Grow[4*k4+3]=gv.w;
        }
        float bvv = (col < NDIM) ? qt[r*NDIM + col] : ws[WS_T1 + r];
        float xv = 0.f, rv = bvv, pv = 0.f, sv = 0.f, gam = 1.f, alf = 1.f;
        for (int it = 0; it < CGIT; ++it){
            rl[g][r] = rv;
            __syncthreads();
            // whole r-vector into 4 VGPRs/lane: lane c holds chunk c = r[4c..4c+3]
            float4 pch = ((const float4*)rl[g])[lane & 31];
            // w = G r via SGPR broadcast (readlane imm) + 4 split FMA chains
            float y0=0.f, y1=0.f, y2=0.f, y3=0.f;
#pragma unroll
            for (int c = 0; c < 32; ++c){
                float p0 = rdl(pch.x, c), p1 = rdl(pch.y, c), p2 = rdl(pch.z, c), p3 = rdl(pch.w, c);
                y0 = fmaf(Grow[4*c+0], p0, y0);
                y1 = fmaf(Grow[4*c+1], p1, y1);
                y2 = fmaf(Grow[4*c+2], p2, y2);
                y3 = fmaf(Grow[4*c+3], p3, y3);
            }
            float w = (y0+y1) + (y2+y3);
            // fused dots: gamma' = (r,r), delta = (w,r)
            float t0 = rv*rv, t1 = w*rv;
#pragma unroll
            for (int d = 1; d < 64; d <<= 1){ t0 += __shfl_xor(t0, d); t1 += __shfl_xor(t1, d); }
            if (lane == 0){ red2[wid][0] = t0; red2[wid][1] = t1; }
            __syncthreads();
            float gp = red2[2*g][0] + red2[2*g+1][0];
            float dl = red2[2*g][1] + red2[2*g+1][1];
            float bet, anew;
            if (it == 0){ bet = 0.f; anew = gp / fmaxf(dl, 1e-30f); }
            else { bet = gp / fmaxf(gam, 1e-30f); anew = gp / fmaxf(dl - bet*gp/alf, 1e-30f); }
            pv = fmaf(bet, pv, rv);
            sv = fmaf(bet, sv, w);
            xv = fmaf(anew, pv, xv);
            rv = fmaf(-anew, sv, rv);
            gam = gp; alf = anew;
        }
        ws[WS_W + r*WN + col] = xv;
    } else {
        // xbar finalize: 8 columns per block, 256 partial rows
        __shared__ float part[8][8];
        int b2 = blockIdx.x - 118;              // 0..58
        int cl = tid & 7, seg = tid >> 3;       // seg 0..63
        int col = b2*8 + cl;
        float acc = 0.f;
        if (col < NDIM){
#pragma unroll
            for (int q = 0; q < 4; ++q) acc += ws[WS_PART + (seg*4 + q)*NDIM + col];
        }
        acc += __shfl_xor(acc, 8);
        acc += __shfl_xor(acc, 16);
        acc += __shfl_xor(acc, 32);
        if (lane < 8) part[wid][lane] = acc;    // lane<8 => cl==lane
        __syncthreads();
        if (tid < 8){
            float t = 0.f;
#pragma unroll
            for (int w2 = 0; w2 < 8; ++w2) t += part[w2][tid];
            int c2 = b2*8 + tid;
            if (c2 < NDIM) ws[WS_XBAR + c2] = t * (1.0f / TD);
        }
    }
}

// ---- Kernel 3: blocks 0..117 W2; 118..588 R rows; 589 Rw = sc*Q^T t2 ----
__global__ __launch_bounds__(256) void k_w2_r(const float* __restrict__ qt, const float* __restrict__ lw,
                                              const float* __restrict__ lb, const float* __restrict__ alpha,
                                              float* __restrict__ ws){
    if (blockIdx.x < 118){
        int lane = threadIdx.x & 63, wid = threadIdx.x >> 6;
        int i = blockIdx.x*4 + wid;
        if (i < NDIM){
            float acc = 0.f;
#pragma unroll
            for (int s = 0; s < 8; ++s){
                int idx = lane + 64*s;
                if (idx < NDIM) acc = fmaf(lw[(size_t)i*NDIM + idx], ws[WS_XBAR + idx], acc);
            }
#pragma unroll
            for (int d = 1; d < 64; d <<= 1) acc += __shfl_xor(acc, d);
            if (lane == 0) ws[WS_W2 + i] = acc + lb[i];
        }
    } else if (blockIdx.x < 589){
        int i = blockIdx.x - 118;           // 0..470 : row i of R
        __shared__ __align__(16) float qc[MD];
        int tid = threadIdx.x, lane = tid & 63;
        if (tid < MD) qc[tid] = qt[tid*NDIM + i];
        __syncthreads();
        float4 qv = ((const float4*)qc)[lane & 31];
        float sc = alpha[0] / (float)NDIM;
        const float* Wp = ws + WS_W;
        int j0 = tid;
        int j1 = (tid + 256 < NDIM) ? tid + 256 : (NDIM - 1);   // clamp (guarded store)
        float a0=0.f, a1=0.f, a2=0.f, a3=0.f;
        float b0=0.f, b1=0.f, b2=0.f, b3=0.f;
#pragma unroll 8
        for (int c = 0; c < 32; ++c){
            float p0 = rdl(qv.x, c), p1 = rdl(qv.y, c), p2 = rdl(qv.z, c), p3 = rdl(qv.w, c);
            const float* W0 = Wp + (4*c+0)*WN;
            const float* W1 = Wp + (4*c+1)*WN;
            const float* W2 = Wp + (4*c+2)*WN;
            const float* W3 = Wp + (4*c+3)*WN;
            a0 = fmaf(p0, W0[j0], a0); b0 = fmaf(p0, W0[j1], b0);
            a1 = fmaf(p1, W1[j0], a1); b1 = fmaf(p1, W1[j1], b1);
            a2 = fmaf(p2, W2[j0], a2); b2 = fmaf(p2, W2[j1], b2);
            a3 = fmaf(p3, W3[j0], a3); b3 = fmaf(p3, W3[j1], b3);
        }
        if (j0 < NDIM) ws[WS_R + (size_t)i*NDIM + j0] = sc * ((a0+a1) + (a2+a3));
        if (tid + 256 < NDIM) ws[WS_R + (size_t)i*NDIM + tid + 256] = sc * ((b0+b1) + (b2+b3));
    } else {
        // Rw_i = sc * sum_k qt[k][i] * t2[k],  t2 = W[:,471] = Ginv (Q w)
        __shared__ float t2l[MD];
        int tid = threadIdx.x;
        if (tid < MD) t2l[tid] = ws[WS_W + tid*WN + 471];
        __syncthreads();
        float sc = alpha[0] / (float)NDIM;
        for (int i = tid; i < NDIM; i += 256){
            float a0=0.f, a1=0.f, a2=0.f, a3=0.f;
#pragma unroll
            for (int k = 0; k < MD; k += 4){
                a0 = fmaf(qt[(k+0)*NDIM + i], t2l[k+0], a0);
                a1 = fmaf(qt[(k+1)*NDIM + i], t2l[k+1], a1);
                a2 = fmaf(qt[(k+2)*NDIM + i], t2l[k+2], a2);
                a3 = fmaf(qt[(k+3)*NDIM + i], t2l[k+3], a3);
            }
            ws[WS_RW + i] = sc * ((a0+a1) + (a2+a3));
        }
    }
}

// ---- Kernel 4: the 10-iteration solver (single block; prefetched matvec) ----
__global__ __launch_bounds__(512, 2) void k_iter(const float* __restrict__ wv,
                                              const float* __restrict__ alpha, const float* __restrict__ lamda,
                                              const float* __restrict__ rho_p, const float* __restrict__ mu_p,
                                              const float* __restrict__ ws, float* __restrict__ out){
    int tid = threadIdx.x, lane = tid & 63, wid = tid >> 6;
    bool act = tid < NDIM;
    int ti = act ? tid : 0;                      // clamped index for always-valid loads
    float rho = rho_p[0], mu = mu_p[0], lam = lamda[0];
    float sc  = alpha[0] / (float)NDIM;
    float wi  = act ? wv[tid]         : 0.f;
    float W2i = act ? ws[WS_W2 + tid] : 0.f;
    float Rwi = act ? ws[WS_RW + tid] : 0.f;

    __shared__ __align__(16) unsigned bins[1024];   // 4 buffers x 256 bins
    __shared__ __align__(8) float2 spair[64];       // packed (idx_bits, weight) support list
    __shared__ float warr[8];
    __shared__ unsigned wcnt[8];

    bins[tid] = 0u; bins[tid + 512] = 0u;
    __syncthreads();

    float z = 0.f, u = 0.f, Ruv = 0.f, Rzv = 0.f, Sz = 0.f;
    for (int it = 0; it < 10; ++it){
        float Rv = Ruv - rho*(Rzv - Rwi);
        float b  = wi + Rv;
        float grad = W2i + rho*(z - b) + u + 2.f*lam*(Sz - 1.f);
        float zn = z - mu*grad;
        zn = (act && zn > 0.f) ? zn : 0.f;
        unsigned bits = __float_as_uint(zn);

        // radix select: 1 barrier/pass; per-pass private bin buffer; redundant per-wave scan
        unsigned prefix = 0, need = KSEL;
#pragma unroll
        for (int pass = 3; pass >= 0; --pass){
            int sh = pass*8;
            unsigned* bp = bins + ((3 - pass) << 8);
            bool av = (pass == 3) || ((bits >> (sh + 8)) == (prefix >> (sh + 8)));
            if (av) atomicAdd(&bp[(bits >> sh) & 255u], 1u);
            __syncthreads();
            int base = 255 - 4*lane;
            uint4 bq = *(const uint4*)&bp[base - 3];
            unsigned b3 = bq.x, b2 = bq.y, b1 = bq.z, b0 = bq.w;   // b0 = bp[base] (highest)
            unsigned csum = b0 + b1 + b2 + b3;
            unsigned incl = csum;
#pragma unroll
            for (int d = 1; d < 64; d <<= 1){ unsigned t = __shfl_up(incl, d); if (lane >= d) incl += t; }
            unsigned excl = incl - csum;
            bool hit = (excl < need) && (need <= incl);
            unsigned long long hm = __ballot(hit);
            int hl = __ffsll((long long)hm) - 1;
            unsigned c0 = excl + b0, c1 = c0 + b1, c2 = c1 + b2;
            int byte; unsigned above;
            if      (need <= c0){ byte = base;   above = excl; }
            else if (need <= c1){ byte = base-1; above = c0; }
            else if (need <= c2){ byte = base-2; above = c1; }
            else                { byte = base-3; above = c2; }
            byte  = __shfl(byte, hl);
            above = (unsigned)__shfl((int)above, hl);
            prefix |= ((unsigned)byte) << sh;
            need -= above;
        }
        z = (act && bits >= prefix) ? zn : 0.f;

        // Sz + support list
        bool flag = z > 0.f;
        unsigned long long mb = __ballot(flag);
        float v = z;
#pragma unroll
        for (int d = 1; d < 64; d <<= 1) v += __shfl_xor(v, d);
        if (lane == 0){ warr[wid] = v; wcnt[wid] = (unsigned)__popcll(mb); }
        __syncthreads();
        Sz = ((warr[0]+warr[1])+(warr[2]+warr[3])) + ((warr[4]+warr[5])+(warr[6]+warr[7]));

        if (it < 9){
            unsigned off = 0;
#pragma unroll
            for (int w2 = 0; w2 < 8; ++w2) if (w2 < wid) off += wcnt[w2];
            off += (unsigned)__popcll(mb & ((1ull << lane) - 1ull));
            int cnt = 0;
#pragma unroll
            for (int w2 = 0; w2 < 8; ++w2) cnt += (int)wcnt[w2];
            if (flag){ spair[off] = make_float2(__int_as_float(tid), z); }
            if (tid >= cnt && tid < 64){ spair[tid] = make_float2(__int_as_float(0), 0.f); }  // exact pad
            bins[tid] = 0u; bins[tid + 512] = 0u;   // re-zero for next iteration
            __syncthreads();

            // one ds_read_b64/thread; (idx,weight) broadcast via readlane imm -> SGPR
            float2 pp = spair[lane];
            const float* Rb = ws + WS_R;
            // phase 1: issue all 56 loads (SGPR row base + coalesced tid offset)
            float rvv[56];
#pragma unroll
            for (int s = 0; s < 56; ++s){
                int j = __float_as_int(rdl(pp.x, s));
                rvv[s] = Rb[(size_t)j*NDIM + ti];
            }
            // phase 2: accumulate with SGPR weights, 4 chains
            float a0=0.f, a1=0.f, a2=0.f, a3=0.f;
#pragma unroll
            for (int s = 0; s < 56; s += 4){
                a0 = fmaf(rvv[s+0], rdl(pp.y, s+0), a0);
                a1 = fmaf(rvv[s+1], rdl(pp.y, s+1), a1);
                a2 = fmaf(rvv[s+2], rdl(pp.y, s+2), a2);
                a3 = fmaf(rvv[s+3], rdl(pp.y, s+3), a3);
            }
            float acc = (a0+a1) + (a2+a3);
            float Rbv = Rwi + sc*Rv;                // R@b = Rw + (alpha/N)*Rv   (P^2 = P)
            u   += rho*(z - b);
            Ruv += rho*(acc - Rbv);
            Rzv  = acc;
        }
    }
    if (act) out[tid] = z / (Sz + 1e-8f);
}

extern "C" void kernel_launch(void* const* d_in, const int* in_sizes, int n_in,
                              void* d_out, int out_size, void* d_ws, size_t ws_size,
                              hipStream_t stream) {
    const float* x     = (const float*)d_in[0];
    const float* qt    = (const float*)d_in[1];
    const float* wv    = (const float*)d_in[2];
    // d_in[3] = b1 (unused by forward math)
    const float* alpha = (const float*)d_in[4];
    const float* lamda = (const float*)d_in[5];
    const float* rho   = (const float*)d_in[6];
    const float* mu    = (const float*)d_in[7];
    const float* lw    = (const float*)d_in[8];
    const float* lb    = (const float*)d_in[9];
    float* out = (float*)d_out;
    float* ws  = (float*)d_ws;

    k_gram_colsum<<<513, 512, 0, stream>>>(qt, x, wv, ws);
    k_cg_xbar    <<<177, 512, 0, stream>>>(qt, ws);
    k_w2_r       <<<590, 256, 0, stream>>>(qt, lw, lb, alpha, ws);
    k_iter       <<<1,   512, 0, stream>>>(wv, alpha, lamda, rho, mu, ws, out);
}